// Round 12
// baseline (99.627 us; speedup 1.0000x reference)
//
#include <hip/hip_runtime.h>

typedef _Float16 f16x4 __attribute__((ext_vector_type(4)));
typedef _Float16 f16x8 __attribute__((ext_vector_type(8)));
typedef unsigned short u16x8 __attribute__((ext_vector_type(8)));
typedef float f32x4 __attribute__((ext_vector_type(4)));

#define NS 1024
#define NQ 1024
#define DD 128
#define NWAY 8
#define SCHUNK 32            // supports per block (2 s-subtiles x 16)
#define NSBLK (NS / SCHUNK)  // 32
#define QPER 16              // queries per block -> grid 32 x 64 = 2048

// d_ws layout (bytes):
//   0x000000  part  [NSBLK][NQ][NWAY] f32  (1 MB)
//   0x100000  sup16 [NS][DD] f16           (256 KB)
//   0x140000  q16   [NQ][DD] f16           (256 KB)
//   0x180000  w1f   [16 frag][64 lane][8] f16 (16 KB, fragment-ordered)

// Prep: one-time f32->f16 conversion of support/query/W1 (W1 directly in
// MFMA fragment order). Keeping conversions out of main removes the
// float4/cvt peak register pressure that drove the R3/R5/R7 spills.
__global__ void siamese_prep(const float* __restrict__ sx,
                             const float* __restrict__ qx,
                             const float* __restrict__ W1,
                             _Float16* __restrict__ sup16,
                             _Float16* __restrict__ q16,
                             _Float16* __restrict__ w1f)
{
    const int tid = blockIdx.x * 256 + threadIdx.x;
    if (blockIdx.x < 128) {                       // support: 32768 float4
        float4 v = ((const float4*)sx)[tid];
        f16x4 h; h[0] = (_Float16)v.x; h[1] = (_Float16)v.y;
        h[2] = (_Float16)v.z; h[3] = (_Float16)v.w;
        ((f16x4*)sup16)[tid] = h;
    } else if (blockIdx.x < 256) {                // query: 32768 float4
        const int i = tid - 32768;
        float4 v = ((const float4*)qx)[i];
        f16x4 h; h[0] = (_Float16)v.x; h[1] = (_Float16)v.y;
        h[2] = (_Float16)v.z; h[3] = (_Float16)v.w;
        ((f16x4*)q16)[i] = h;
    } else {                                      // W1 frags: 16*64 = 1024
        const int i = tid - 65536;
        const int jk = i >> 6, l = i & 63;
        const int h = (jk >> 2) * 16 + (l & 15);
        const int d = (jk & 3) * 32 + (l >> 4) * 8;
        const float* wp = W1 + h * DD + d;
        float4 v0 = *(const float4*)(wp);
        float4 v1 = *(const float4*)(wp + 4);
        f16x8 s;
        s[0] = (_Float16)v0.x; s[1] = (_Float16)v0.y;
        s[2] = (_Float16)v0.z; s[3] = (_Float16)v0.w;
        s[4] = (_Float16)v1.x; s[5] = (_Float16)v1.y;
        s[6] = (_Float16)v1.z; s[7] = (_Float16)v1.w;
        *(f16x8*)(w1f + (size_t)i * 8) = s;
    }
}

// Main: 32 supports x 16 queries per block, grid 2048.
// Wave split (R5 structure, retried now that prep removed the cvt
// pressure): wave = (jh<<1)|ws; ws picks the s-subtile (16 supports),
// jh picks the h-half (h = (jh*2+j2)*16 + quad*4 + r). Both jh-waves add
// their partial sims into the same clsbuf[qq][cls] LDS atomic — b1 is
// seeded per-h so nothing double-counts.
// sim(q,s) = relu(|q-s| @ W1^T + b1) @ W2; b2 dropped (log_softmax
// shift-invariant). MFMA: A = W1 frag, B = diff frag -> C rows h, cols s;
// h-reduction = per-lane fma + 2 cross-quad shuffles.
// Live set ~100 regs (afrag 32, sup 16, qf 16, acc 8, b1/w2 16) ->
// launch_bounds(256,3) (~170 cap) should hold WITHOUT the spills that
// killed R3/R5/R7 (their spike came from inline f32->f16 conversion).
// TRIPWIRE: WRITE_SIZE must stay ~1 MB; tens of MB = spill -> revert.
__global__ __launch_bounds__(256, 3) void siamese_main(
    const _Float16* __restrict__ sup16,
    const int* __restrict__ support_y,
    const _Float16* __restrict__ q16,
    const _Float16* __restrict__ w1f,
    const float* __restrict__ b1,
    const float* __restrict__ W2,
    float* __restrict__ part)   // [NSBLK][NQ][NWAY]
{
    __shared__ _Float16 qtile[QPER][DD];       // 4 KB
    __shared__ float clsbuf[QPER][NWAY];       // 512 B

    const int t = threadIdx.x;
    const int wave = t >> 6;
    const int lane = t & 63;
    const int c = lane & 15;     // MFMA n index -> support col
    const int quad = lane >> 4;  // MFMA k-group / C row-group

    const int ws = wave & 1;     // s-subtile
    const int jh = wave >> 1;    // h-half

    const int sblk = blockIdx.x & (NSBLK - 1);
    const int qblk = blockIdx.x >> 5;
    const int s0 = sblk * SCHUNK;
    const int q0 = qblk * QPER;

    // ---- one-time: support B-fragments (pure f16 16B loads) ----
    f16x8 sup[4];
    {
        const _Float16* sp = sup16 + (size_t)(s0 + ws * 16 + c) * DD + quad * 8;
#pragma unroll
        for (int k = 0; k < 4; ++k)
            sup[k] = *(const f16x8*)(sp + k * 32);
    }

    // ---- one-time: W1 A-fragments for this h-half (16B loads) ----
    f16x8 afrag[2][4];
#pragma unroll
    for (int j2 = 0; j2 < 2; ++j2)
#pragma unroll
        for (int k = 0; k < 4; ++k)
            afrag[j2][k] = *(const f16x8*)(
                w1f + (size_t)(((jh * 2 + j2) * 4 + k) * 64 + lane) * 8);

    // ---- one-time: b1/W2 rows (h = (jh*2+j2)*16 + quad*4 + r) ----
    f32x4 b1v[2], w2v[2];
#pragma unroll
    for (int j2 = 0; j2 < 2; ++j2) {
        b1v[j2] = *(const f32x4*)(b1 + (jh * 2 + j2) * 16 + quad * 4);
        w2v[j2] = *(const f32x4*)(W2 + (jh * 2 + j2) * 16 + quad * 4);
    }

    const int lbl = support_y[s0 + ws * 16 + c];

    // ---- stage QPER query rows (f16, direct 16B copies) ----
    {
        const int q = t >> 4;
        const int dd = (t & 15) * 8;
        *(f16x8*)&qtile[q][dd] = *(const f16x8*)(q16 + (size_t)(q0 + q) * DD + dd);
    }
    if (t < QPER * NWAY) clsbuf[t >> 3][t & 7] = 0.f;
    __syncthreads();

    for (int qq = 0; qq < QPER; ++qq) {
        // quad-uniform broadcast reads of the query slice
        f16x8 qf[4];
#pragma unroll
        for (int k = 0; k < 4; ++k)
            qf[k] = *(const f16x8*)&qtile[qq][k * 32 + quad * 8];

        // accumulators pre-seeded with this wave's b1 rows
        f32x4 acc[2];
        acc[0] = b1v[0];
        acc[1] = b1v[1];

#pragma unroll
        for (int k = 0; k < 4; ++k) {
            union { f16x8 f; u16x8 u; } cv;
            cv.f = sup[k] - qf[k];
            cv.u = cv.u & (unsigned short)0x7fffu;  // |diff|
#pragma unroll
            for (int j2 = 0; j2 < 2; ++j2)
                acc[j2] = __builtin_amdgcn_mfma_f32_16x16x32_f16(
                    afrag[j2][k], cv.f, acc[j2], 0, 0, 0);
        }

        // epilogue: partial sim over this wave's 32 h
        float val = 0.f;
#pragma unroll
        for (int j2 = 0; j2 < 2; ++j2)
#pragma unroll
            for (int r = 0; r < 4; ++r)
                val = fmaf(fmaxf(acc[j2][r], 0.f), w2v[j2][r], val);
        val += __shfl_xor(val, 16);
        val += __shfl_xor(val, 32);
        if (quad == 0) atomicAdd(&clsbuf[qq][lbl], val);
    }
    __syncthreads();

    // one coalesced 128-float store: part[sblk][q0..q0+15][0..7]
    if (t < QPER * NWAY)
        part[(size_t)sblk * (NQ * NWAY) + q0 * NWAY + t] = clsbuf[t >> 3][t & 7];
}

// Finalize: sum NSBLK partials, counts, per-class mean, log_softmax.
// Grid 8 x 128 threads (one thread per query).
__global__ void siamese_finalize(
    const int* __restrict__ support_y,
    const float* __restrict__ part,
    float* __restrict__ out)
{
    __shared__ float cnt[NWAY];
    const int t = threadIdx.x;
    if (t < NWAY) cnt[t] = 0.f;
    __syncthreads();
#pragma unroll
    for (int i = 0; i < NS / 128; ++i)
        atomicAdd(&cnt[support_y[t * (NS / 128) + i]], 1.0f);
    __syncthreads();

    const int q = blockIdx.x * 128 + t;
    float lg[NWAY];
    float mx = -1e30f;
#pragma unroll
    for (int k = 0; k < NWAY; ++k) {
        float s = 0.f;
#pragma unroll
        for (int sb = 0; sb < NSBLK; ++sb)
            s += part[(size_t)sb * (NQ * NWAY) + q * NWAY + k];
        lg[k] = s / cnt[k];
        mx = fmaxf(mx, lg[k]);
    }
    float ss = 0.f;
#pragma unroll
    for (int k = 0; k < NWAY; ++k) ss += expf(lg[k] - mx);
    const float lse = mx + logf(ss);
#pragma unroll
    for (int k = 0; k < NWAY; ++k) out[q * NWAY + k] = lg[k] - lse;
}

extern "C" void kernel_launch(void* const* d_in, const int* in_sizes, int n_in,
                              void* d_out, int out_size, void* d_ws, size_t ws_size,
                              hipStream_t stream) {
    const float* support_x = (const float*)d_in[0];
    const int* support_y   = (const int*)d_in[1];
    const float* query_x   = (const float*)d_in[2];
    // d_in[3] = n_way (scalar, fixed at 8) — unused
    const float* W1 = (const float*)d_in[4];
    const float* b1 = (const float*)d_in[5];
    const float* W2 = (const float*)d_in[6];
    // d_in[7] = b2 — dropped (uniform logit shift, log_softmax-invariant)

    char* ws = (char*)d_ws;
    float* part       = (float*)(ws);                  // 1 MB
    _Float16* sup16   = (_Float16*)(ws + 0x100000);    // 256 KB
    _Float16* q16     = (_Float16*)(ws + 0x140000);    // 256 KB
    _Float16* w1f     = (_Float16*)(ws + 0x180000);    // 16 KB

    siamese_prep<<<dim3(260), dim3(256), 0, stream>>>(
        support_x, query_x, W1, sup16, q16, w1f);
    siamese_main<<<dim3(NSBLK * (NQ / QPER)), dim3(256), 0, stream>>>(
        sup16, support_y, q16, w1f, b1, W2, part);
    siamese_finalize<<<dim3(NQ / 128), dim3(128), 0, stream>>>(
        support_y, part, (float*)d_out);
}